// Round 8
// baseline (74.055 us; speedup 1.0000x reference)
//
#include <hip/hip_runtime.h>

#define IN_CH 3
#define OUT_CH 32
#define IN_FEAT 27
#define NB 5
#define NG 8
#define HH 256
#define WW 256
#define NPIX (16 * HH * WW)

// Phi record: 24 fp16 payload, padded to 28 halves (56 B) in LDS
#define RECE 24
#define RECP 28
#define TW 66                            // halo tile width (64 + 2)
#define TROWS 6                          // halo rows (4 + 2)
#define NREC (TROWS * TW)                // 396 records per tile
#define NTILES 8                         // tiles per strip block (32 rows)
#define WB_HALVES (9 * 2 * 64 * 8)       // 9216 halves = 18432 B
#define WS_NEEDED ((size_t)WB_HALVES * 2 + 16)

typedef __attribute__((ext_vector_type(8))) _Float16 half8;
typedef __attribute__((ext_vector_type(4))) float f32x4;

// Reference-exact phi (Cox-de Boor) -- prep + fallback only
__device__ inline void kan_phi6(float xx, const float* g, const float* r1, const float* r2,
                                float* o6) {
    const float sig = 1.0f / (1.0f + __expf(-xx));
    o6[0] = xx * sig;
    float b0[7];
#pragma unroll
    for (int j = 0; j < 7; ++j) b0[j] = (xx >= g[j] && xx < g[j + 1]) ? 1.0f : 0.0f;
    float b1[6];
#pragma unroll
    for (int j = 0; j < 6; ++j)
        b1[j] = (xx - g[j]) * r1[j] * b0[j] + (g[j + 2] - xx) * r1[j + 1] * b0[j + 1];
#pragma unroll
    for (int j = 0; j < NB; ++j)
        o6[1 + j] = (xx - g[j]) * r2[j] * b1[j] + (g[j + 3] - xx) * r2[j + 1] * b1[j + 1];
}

__device__ inline void load_grid(const float* __restrict__ grid, float* g, float* r1, float* r2) {
#pragma unroll
    for (int j = 0; j < NG; ++j) g[j] = grid[j];
#pragma unroll
    for (int j = 0; j < NG - 1; ++j) r1[j] = 1.0f / (g[j + 1] - g[j]);
#pragma unroll
    for (int j = 0; j < NG - 2; ++j) r2[j] = 1.0f / (g[j + 2] - g[j]);
}

// ---------------------------------------------------------------------------
// Prep: weights -> exact B-fragment layout (fp16). wb[((tap*2+nt)*64+lane)*8+e]
// Thread 0 also writes {g0, invh} after wb (grid is uniform).
// ---------------------------------------------------------------------------
__global__ void kan_prepW(const float* __restrict__ bw, const float* __restrict__ sw,
                          const float* __restrict__ ss, const float* __restrict__ grid,
                          _Float16* __restrict__ wb) {
    int t = blockIdx.x * 256 + threadIdx.x;
    if (t >= 9 * 2 * 64) return;

    if (t == 0) {
        float* gt = (float*)(wb + WB_HALVES);
        gt[0] = grid[0];
        gt[1] = 7.0f / (grid[7] - grid[0]);   // 1/h
    }

    const int lane = t & 63;
    const int nt = (t >> 6) & 1;
    const int tap = t >> 7;
    const int o = nt * 16 + (lane & 15);
    const int kbase = (lane >> 4) * 8;
    half8 v8 = {0, 0, 0, 0, 0, 0, 0, 0};
#pragma unroll
    for (int e = 0; e < 8; ++e) {
        int kk = kbase + e;
        float v = 0.0f;
        if (kk < 18) {
            int c = kk / 6, j = kk % 6;
            int f = c * 9 + tap;
            int of = o * IN_FEAT + f;
            v = (j == 0) ? bw[of] : sw[of * NB + (j - 1)] * ss[of];
        }
        v8[e] = (_Float16)v;
    }
    *(half8*)(wb + (size_t)t * 8) = v8;
}

// ---------------------------------------------------------------------------
// Fused strip kernel: block = 256 thr = 4 waves; strip = 64 wide x 32 rows
// = 8 tiles of 64x4, software-pipelined with double-buffered LDS:
//   iter t: issue x-loads(t+1) -> regs | MFMA+store tile t from buf[cur]
//           | phi-convert -> buf[cur^1] | one barrier.
// ---------------------------------------------------------------------------
__global__ __launch_bounds__(256, 2) void kan_fused(const float* __restrict__ x,
                                                    const _Float16* __restrict__ wb,
                                                    float* __restrict__ out) {
    __shared__ _Float16 lPhi[2][NREC * RECP];   // 2 x 22176 B

    const int tid = threadIdx.x;
    const int bid = blockIdx.x;
    const int strip = bid & 3;                   // w-strip
    const int hband = (bid >> 2) & 7;            // 32-row band
    const int b = bid >> 5;
    const int h0 = hband * 32;
    const int w0 = strip * 64;

    const int lane = tid & 63;
    const int wid = tid >> 6;
    const int r = lane & 15;      // A row (pixel) / B col (channel) within tile
    const int gq = lane >> 4;     // k-group (0..3); gq==3 -> zero pad

    // B-fragments: straight from global (L2-resident), once per thread
    half8 bf[18];
#pragma unroll
    for (int i = 0; i < 18; ++i)
        bf[i] = *(const half8*)(wb + ((size_t)(i * 64 + lane)) * 8);

    const float* gt = (const float*)(wb + WB_HALVES);
    const float g0 = gt[0];
    const float invh = gt[1];

    // per-thread halo record coords (2 records: tid, tid+256)
    const int ri0 = tid;
    const int ri1 = tid + 256;                   // valid iff < NREC (tid < 140)
    const int dy0 = ri0 / TW, wx0r = ri0 - dy0 * TW - 1;
    const int dy1 = ri1 / TW, wx1r = ri1 - dy1 * TW - 1;
    const int wx0 = w0 + wx0r, wx1 = w0 + wx1r;
    const bool cOK0 = ((unsigned)wx0 < WW);
    const bool cOK1 = (ri1 < NREC) && ((unsigned)wx1 < WW);

    float xr0[IN_CH], xr1[IN_CH];

    // ---- load x for tile t's halo into regs (no wait) ----
    auto issue_loads = [&](int t) {
        const int hbase = h0 + t * 4 - 1;
        const int hy0 = hbase + dy0;
        const int hy1 = hbase + dy1;
        const bool v0 = cOK0 & ((unsigned)hy0 < HH);
        const bool v1 = cOK1 & ((unsigned)hy1 < HH);
#pragma unroll
        for (int c = 0; c < IN_CH; ++c) {
            xr0[c] = v0 ? x[((b * IN_CH + c) << 16) + (hy0 << 8) + wx0] : 0.0f;
            xr1[c] = v1 ? x[((b * IN_CH + c) << 16) + (hy1 << 8) + wx1] : 0.0f;
        }
    };

    // ---- convert regs -> phi records in LDS buffer ----
    auto convert = [&](int buf) {
        _Float16* dstb = lPhi[buf];
#pragma unroll
        for (int k = 0; k < 2; ++k) {
            const int ri = k ? ri1 : ri0;
            if (k && ri1 >= NREC) break;
            const float* xr = k ? xr1 : xr0;
            _Float16 rec[RECE];
#pragma unroll
            for (int c = 0; c < IN_CH; ++c) {
                const float xx = xr[c];
                const float sig = 1.0f / (1.0f + __expf(-xx));
                rec[c * 6] = (_Float16)(xx * sig);
                const float u = (xx - g0) * invh;
                const float fi = floorf(u);
                const int i0 = (int)fi;
                const float t = u - fi;
                const float om = 1.0f - t;
                float wA = 0.5f * om * om;
                float wC = 0.5f * t * t;
                float wB = 1.0f - wA - wC;
                const bool valid = (fi >= 0.0f) & (i0 <= 6);
                wA = valid ? wA : 0.0f;
                wB = valid ? wB : 0.0f;
                wC = valid ? wC : 0.0f;
#pragma unroll
                for (int j = 0; j < NB; ++j) {
                    float v = (j == i0 - 2) ? wA : ((j == i0 - 1) ? wB : ((j == i0) ? wC : 0.0f));
                    rec[c * 6 + 1 + j] = (_Float16)v;
                }
            }
#pragma unroll
            for (int j = 18; j < RECE; ++j) rec[j] = (_Float16)0.0f;
            half8* dst = (half8*)(dstb + ri * RECP);
            dst[0] = *(half8*)(rec + 0);
            dst[1] = *(half8*)(rec + 8);
            dst[2] = *(half8*)(rec + 16);
        }
    };

    // ---- prologue: tile 0 ----
    issue_loads(0);
    convert(0);
    __syncthreads();

    int cur = 0;
    for (int t = 0; t < NTILES; ++t) {
        const bool more = (t + 1 < NTILES);
        if (more) issue_loads(t + 1);            // in flight during MFMA phase

        // ---- MFMA + store tile t: wave wid owns row h0 + t*4 + wid ----
        const _Float16* lp = lPhi[cur];
        const int hrow = h0 + t * 4 + wid;
        float* pb0 = out + ((size_t)(b * OUT_CH + r) << 16)      + (hrow << 8) + w0 + gq * 4;
        float* pb1 = out + ((size_t)(b * OUT_CH + 16 + r) << 16) + (hrow << 8) + w0 + gq * 4;
#pragma unroll
        for (int m = 0; m < 4; ++m) {
            half8 af[9];
#pragma unroll
            for (int dy = 0; dy < 3; ++dy) {
#pragma unroll
                for (int dx = 0; dx < 3; ++dx) {
                    const int ridx = (wid + dy) * TW + m * 16 + r + dx;
                    half8 v = {0, 0, 0, 0, 0, 0, 0, 0};
                    if (gq < 3) v = *(const half8*)(lp + ridx * RECP + gq * 8);
                    af[dy * 3 + dx] = v;
                }
            }
            f32x4 acc0 = {0.f, 0.f, 0.f, 0.f};
            f32x4 acc1 = {0.f, 0.f, 0.f, 0.f};
#pragma unroll
            for (int tap = 0; tap < 9; ++tap) {
                acc0 = __builtin_amdgcn_mfma_f32_16x16x32_f16(af[tap], bf[tap * 2 + 0], acc0, 0, 0, 0);
                acc1 = __builtin_amdgcn_mfma_f32_16x16x32_f16(af[tap], bf[tap * 2 + 1], acc1, 0, 0, 0);
            }
            *(f32x4*)(pb0 + m * 16) = acc0;
            *(f32x4*)(pb1 + m * 16) = acc1;
        }

        // ---- phi for tile t+1 into the other buffer ----
        if (more) convert(cur ^ 1);
        __syncthreads();
        cur ^= 1;
    }
}

// ===========================================================================
// Fallback (round-1 fp32 path) if ws_size is too small for wb
// ===========================================================================
__global__ void kan_combine_weights(const float* __restrict__ bw,
                                    const float* __restrict__ sw,
                                    const float* __restrict__ ss,
                                    float* __restrict__ wc) {
    int idx = blockIdx.x * blockDim.x + threadIdx.x;
    if (idx >= IN_FEAT * 6 * OUT_CH) return;
    int o = idx & 31;
    int j = (idx >> 5) % 6;
    int f = idx / (6 * 32);
    float v;
    if (j == 0) v = bw[o * IN_FEAT + f];
    else        v = sw[(o * IN_FEAT + f) * NB + (j - 1)] * ss[o * IN_FEAT + f];
    wc[idx] = v;
}

__global__ __launch_bounds__(256) void kan_main(const float* __restrict__ x,
                                                const float* __restrict__ grid,
                                                const float* __restrict__ wc,
                                                float* __restrict__ out) {
    const int p = blockIdx.x * blockDim.x + threadIdx.x;
    const int w = p & (WW - 1);
    const int h = (p >> 8) & (HH - 1);
    const int b = p >> 16;
    float g[NG], r1[NG - 1], r2[NG - 2];
    load_grid(grid, g, r1, r2);
    float acc[OUT_CH];
#pragma unroll
    for (int o = 0; o < OUT_CH; ++o) acc[o] = 0.0f;
    const float* xb = x + b * (IN_CH * HH * WW);
    for (int c = 0; c < IN_CH; ++c) {
        const float* xc = xb + c * (HH * WW);
#pragma unroll
        for (int dy = 0; dy < 3; ++dy) {
            const int hy = h + dy - 1;
            const bool vy = (hy >= 0) && (hy < HH);
#pragma unroll
            for (int dx = 0; dx < 3; ++dx) {
                const int wx = w + dx - 1;
                const bool vld = vy && (wx >= 0) && (wx < WW);
                const float xx = vld ? xc[hy * WW + wx] : 0.0f;
                float o6[6];
                kan_phi6(xx, g, r1, r2, o6);
                const float* wf = wc + (c * 9 + dy * 3 + dx) * (6 * OUT_CH);
#pragma unroll
                for (int jj = 0; jj < 6; ++jj) {
                    const float* wj = wf + jj * OUT_CH;
#pragma unroll
                    for (int o = 0; o < OUT_CH; ++o) acc[o] += o6[jj] * wj[o];
                }
            }
        }
    }
    float* ob = out + (size_t)b * (OUT_CH * HH * WW) + h * WW + w;
#pragma unroll
    for (int o = 0; o < OUT_CH; ++o) ob[o * (HH * WW)] = acc[o];
}

// ===========================================================================
extern "C" void kernel_launch(void* const* d_in, const int* in_sizes, int n_in,
                              void* d_out, int out_size, void* d_ws, size_t ws_size,
                              hipStream_t stream) {
    const float* x    = (const float*)d_in[0];
    const float* bw   = (const float*)d_in[1];
    const float* sw   = (const float*)d_in[2];
    const float* ss   = (const float*)d_in[3];
    const float* grid = (const float*)d_in[4];
    float* out = (float*)d_out;

    if (ws_size >= WS_NEEDED) {
        _Float16* wb = (_Float16*)d_ws;
        kan_prepW<<<(9 * 2 * 64 + 255) / 256, 256, 0, stream>>>(bw, sw, ss, grid, wb);
        kan_fused<<<NPIX / (64 * 32), 256, 0, stream>>>(x, wb, out);   // 512 blocks
    } else {
        float* wc = (float*)d_ws;
        kan_combine_weights<<<(IN_FEAT * 6 * OUT_CH + 255) / 256, 256, 0, stream>>>(bw, sw, ss, wc);
        kan_main<<<NPIX / 256, 256, 0, stream>>>(x, grid, wc, out);
    }
}

// Round 9
// 56.644 us; speedup vs baseline: 1.3074x; 1.3074x over previous
//
#include <hip/hip_runtime.h>

#define IN_CH 3
#define OUT_CH 32
#define IN_FEAT 27
#define NB 5
#define NG 8
#define HH 256
#define WW 256
#define NPIX (16 * HH * WW)

// Phi record: 24 fp16 payload, padded to 28 halves (56 B) in LDS for bank spread
#define RECE 24
#define RECP 28
#define TW 66                            // halo tile width (64 + 2)
#define TROWS 6                          // halo rows (4 + 2)
#define NREC (TROWS * TW)                // 396 records per block
#define WB_HALVES (9 * 2 * 64 * 8)       // 9216 halves = 18432 B
#define WS_NEEDED ((size_t)WB_HALVES * 2 + 16)

typedef __attribute__((ext_vector_type(8))) _Float16 half8;
typedef __attribute__((ext_vector_type(4))) float f32x4;

// Reference-exact phi (Cox-de Boor) -- fallback only
__device__ inline void kan_phi6(float xx, const float* g, const float* r1, const float* r2,
                                float* o6) {
    const float sig = 1.0f / (1.0f + __expf(-xx));
    o6[0] = xx * sig;
    float b0[7];
#pragma unroll
    for (int j = 0; j < 7; ++j) b0[j] = (xx >= g[j] && xx < g[j + 1]) ? 1.0f : 0.0f;
    float b1[6];
#pragma unroll
    for (int j = 0; j < 6; ++j)
        b1[j] = (xx - g[j]) * r1[j] * b0[j] + (g[j + 2] - xx) * r1[j + 1] * b0[j + 1];
#pragma unroll
    for (int j = 0; j < NB; ++j)
        o6[1 + j] = (xx - g[j]) * r2[j] * b1[j] + (g[j + 3] - xx) * r2[j + 1] * b1[j + 1];
}

__device__ inline void load_grid(const float* __restrict__ grid, float* g, float* r1, float* r2) {
#pragma unroll
    for (int j = 0; j < NG; ++j) g[j] = grid[j];
#pragma unroll
    for (int j = 0; j < NG - 1; ++j) r1[j] = 1.0f / (g[j + 1] - g[j]);
#pragma unroll
    for (int j = 0; j < NG - 2; ++j) r2[j] = 1.0f / (g[j + 2] - g[j]);
}

// ---------------------------------------------------------------------------
// Prep: weights -> exact B-fragment layout (fp16). wb[((tap*2+nt)*64+lane)*8+e]
// Thread 0 also writes {g0, invh} after wb (grid is uniform: h = 2/3).
// ---------------------------------------------------------------------------
__global__ void kan_prepW(const float* __restrict__ bw, const float* __restrict__ sw,
                          const float* __restrict__ ss, const float* __restrict__ grid,
                          _Float16* __restrict__ wb) {
    int t = blockIdx.x * 256 + threadIdx.x;
    if (t >= 9 * 2 * 64) return;

    if (t == 0) {
        float* gt = (float*)(wb + WB_HALVES);
        gt[0] = grid[0];
        gt[1] = 7.0f / (grid[7] - grid[0]);   // 1/h
    }

    const int lane = t & 63;
    const int nt = (t >> 6) & 1;
    const int tap = t >> 7;
    const int o = nt * 16 + (lane & 15);
    const int kbase = (lane >> 4) * 8;
    half8 v8 = {0, 0, 0, 0, 0, 0, 0, 0};
#pragma unroll
    for (int e = 0; e < 8; ++e) {
        int kk = kbase + e;
        float v = 0.0f;
        if (kk < 18) {
            int c = kk / 6, j = kk % 6;
            int f = c * 9 + tap;
            int of = o * IN_FEAT + f;
            v = (j == 0) ? bw[of] : sw[of * NB + (j - 1)] * ss[of];
        }
        v8[e] = (_Float16)v;
    }
    *(half8*)(wb + (size_t)t * 8) = v8;
}

// ---------------------------------------------------------------------------
// Fused kernel (R6 geometry): block = 256 thr = 4 waves; tile = 64 x 4 rows.
//  Phase 1: 396 halo records (6x66) -> LDS, closed-form uniform B-spline.
//  Phase 2: wave wid owns row h0+wid: 4 M-tiles x 9 taps x 2 N -> 72 MFMA;
//           B-frags register-resident; nontemporal dwordx4 stores.
// ---------------------------------------------------------------------------
__global__ __launch_bounds__(256) void kan_fused(const float* __restrict__ x,
                                                 const _Float16* __restrict__ wb,
                                                 float* __restrict__ out) {
    __shared__ _Float16 lPhi[NREC * RECP];   // 22176 B

    const int tid = threadIdx.x;
    const int bid = blockIdx.x;
    const int strip = bid & 3;
    const int rowg = (bid >> 2) & 63;
    const int b = bid >> 8;
    const int h0 = rowg * 4;
    const int w0 = strip * 64;

    const int lane = tid & 63;
    const int wid = tid >> 6;
    const int r = lane & 15;      // A row (pixel) / B col (channel) within tile
    const int gq = lane >> 4;     // k-group (0..3); gq==3 -> zero pad

    // ---- B-fragments: straight from global (L2-resident), once per thread ----
    half8 bf[18];
#pragma unroll
    for (int i = 0; i < 18; ++i)
        bf[i] = *(const half8*)(wb + ((size_t)(i * 64 + lane)) * 8);

    const float* gt = (const float*)(wb + WB_HALVES);
    const float g0 = gt[0];
    const float invh = gt[1];

    // ---- Phase 1: phi halo tile (closed-form uniform quadratic B-spline) ----
    for (int ri = tid; ri < NREC; ri += 256) {
        const int dyR = ri / TW;             // 0..5
        const int wxR = ri - dyR * TW - 1;   // -1..64
        const int hy = h0 + dyR - 1;
        const int wx = w0 + wxR;
        const bool vld = ((unsigned)hy < HH) & ((unsigned)wx < WW);

        _Float16 rec[RECE];
#pragma unroll
        for (int c = 0; c < IN_CH; ++c) {
            const float xx = vld ? x[((b * IN_CH + c) << 16) + (hy << 8) + wx] : 0.0f;
            const float sig = 1.0f / (1.0f + __expf(-xx));
            rec[c * 6] = (_Float16)(xx * sig);
            const float u = (xx - g0) * invh;
            const float fi = floorf(u);
            const int i0 = (int)fi;
            const float t = u - fi;
            const float om = 1.0f - t;
            float wA = 0.5f * om * om;          // slot i0-2
            float wC = 0.5f * t * t;            // slot i0
            float wB = 1.0f - wA - wC;          // slot i0-1
            const bool valid = (fi >= 0.0f) & (i0 <= 6);
            wA = valid ? wA : 0.0f;
            wB = valid ? wB : 0.0f;
            wC = valid ? wC : 0.0f;
#pragma unroll
            for (int j = 0; j < NB; ++j) {
                float v = (j == i0 - 2) ? wA : ((j == i0 - 1) ? wB : ((j == i0) ? wC : 0.0f));
                rec[c * 6 + 1 + j] = (_Float16)v;
            }
        }
#pragma unroll
        for (int j = 18; j < RECE; ++j) rec[j] = (_Float16)0.0f;

        half8* dst = (half8*)(lPhi + ri * RECP);
        dst[0] = *(half8*)(rec + 0);
        dst[1] = *(half8*)(rec + 8);
        dst[2] = *(half8*)(rec + 16);
    }
    __syncthreads();

    // ---- Phase 2: 4 M-tiles along the wave's row ----
    const int hrow = h0 + wid;
    float* pb0 = out + ((size_t)(b * OUT_CH + r) << 16)      + (hrow << 8) + w0 + gq * 4;
    float* pb1 = out + ((size_t)(b * OUT_CH + 16 + r) << 16) + (hrow << 8) + w0 + gq * 4;
#pragma unroll
    for (int m = 0; m < 4; ++m) {
        half8 af[9];
#pragma unroll
        for (int dy = 0; dy < 3; ++dy) {
#pragma unroll
            for (int dx = 0; dx < 3; ++dx) {
                const int ridx = (wid + dy) * TW + m * 16 + r + dx;
                half8 v = {0, 0, 0, 0, 0, 0, 0, 0};
                if (gq < 3) v = *(const half8*)(lPhi + ridx * RECP + gq * 8);
                af[dy * 3 + dx] = v;
            }
        }

        f32x4 acc0 = {0.f, 0.f, 0.f, 0.f};
        f32x4 acc1 = {0.f, 0.f, 0.f, 0.f};
#pragma unroll
        for (int tap = 0; tap < 9; ++tap) {
            acc0 = __builtin_amdgcn_mfma_f32_16x16x32_f16(af[tap], bf[tap * 2 + 0], acc0, 0, 0, 0);
            acc1 = __builtin_amdgcn_mfma_f32_16x16x32_f16(af[tap], bf[tap * 2 + 1], acc1, 0, 0, 0);
        }

        // Nontemporal direct stores (streamed output, never re-read)
        __builtin_nontemporal_store(acc0, (f32x4*)(pb0 + m * 16));
        __builtin_nontemporal_store(acc1, (f32x4*)(pb1 + m * 16));
    }
}

// ===========================================================================
// Fallback (round-1 fp32 path) if ws_size is too small for wb
// ===========================================================================
__global__ void kan_combine_weights(const float* __restrict__ bw,
                                    const float* __restrict__ sw,
                                    const float* __restrict__ ss,
                                    float* __restrict__ wc) {
    int idx = blockIdx.x * blockDim.x + threadIdx.x;
    if (idx >= IN_FEAT * 6 * OUT_CH) return;
    int o = idx & 31;
    int j = (idx >> 5) % 6;
    int f = idx / (6 * 32);
    float v;
    if (j == 0) v = bw[o * IN_FEAT + f];
    else        v = sw[(o * IN_FEAT + f) * NB + (j - 1)] * ss[o * IN_FEAT + f];
    wc[idx] = v;
}

__global__ __launch_bounds__(256) void kan_main(const float* __restrict__ x,
                                                const float* __restrict__ grid,
                                                const float* __restrict__ wc,
                                                float* __restrict__ out) {
    const int p = blockIdx.x * blockDim.x + threadIdx.x;
    const int w = p & (WW - 1);
    const int h = (p >> 8) & (HH - 1);
    const int b = p >> 16;
    float g[NG], r1[NG - 1], r2[NG - 2];
    load_grid(grid, g, r1, r2);
    float acc[OUT_CH];
#pragma unroll
    for (int o = 0; o < OUT_CH; ++o) acc[o] = 0.0f;
    const float* xb = x + b * (IN_CH * HH * WW);
    for (int c = 0; c < IN_CH; ++c) {
        const float* xc = xb + c * (HH * WW);
#pragma unroll
        for (int dy = 0; dy < 3; ++dy) {
            const int hy = h + dy - 1;
            const bool vy = (hy >= 0) && (hy < HH);
#pragma unroll
            for (int dx = 0; dx < 3; ++dx) {
                const int wx = w + dx - 1;
                const bool vld = vy && (wx >= 0) && (wx < WW);
                const float xx = vld ? xc[hy * WW + wx] : 0.0f;
                float o6[6];
                kan_phi6(xx, g, r1, r2, o6);
                const float* wf = wc + (c * 9 + dy * 3 + dx) * (6 * OUT_CH);
#pragma unroll
                for (int jj = 0; jj < 6; ++jj) {
                    const float* wj = wf + jj * OUT_CH;
#pragma unroll
                    for (int o = 0; o < OUT_CH; ++o) acc[o] += o6[jj] * wj[o];
                }
            }
        }
    }
    float* ob = out + (size_t)b * (OUT_CH * HH * WW) + h * WW + w;
#pragma unroll
    for (int o = 0; o < OUT_CH; ++o) ob[o * (HH * WW)] = acc[o];
}

// ===========================================================================
extern "C" void kernel_launch(void* const* d_in, const int* in_sizes, int n_in,
                              void* d_out, int out_size, void* d_ws, size_t ws_size,
                              hipStream_t stream) {
    const float* x    = (const float*)d_in[0];
    const float* bw   = (const float*)d_in[1];
    const float* sw   = (const float*)d_in[2];
    const float* ss   = (const float*)d_in[3];
    const float* grid = (const float*)d_in[4];
    float* out = (float*)d_out;

    if (ws_size >= WS_NEEDED) {
        _Float16* wb = (_Float16*)d_ws;
        kan_prepW<<<(9 * 2 * 64 + 255) / 256, 256, 0, stream>>>(bw, sw, ss, grid, wb);
        kan_fused<<<NPIX / 256, 256, 0, stream>>>(x, wb, out);   // 2048 blocks
    } else {
        float* wc = (float*)d_ws;
        kan_combine_weights<<<(IN_FEAT * 6 * OUT_CH + 255) / 256, 256, 0, stream>>>(bw, sw, ss, wc);
        kan_main<<<NPIX / 256, 256, 0, stream>>>(x, grid, wc, out);
    }
}

// Round 10
// 47.061 us; speedup vs baseline: 1.5736x; 1.2036x over previous
//
#include <hip/hip_runtime.h>

#define IN_CH 3
#define OUT_CH 32
#define IN_FEAT 27
#define NB 5
#define NG 8
#define HH 256
#define WW 256
#define NPIX (16 * HH * WW)

// Phi record: 24 fp16 payload (18 real + 6 zero), padded to 28 halves in LDS
#define RECE 24
#define RECP 28
#define TW 66                            // halo tile width (64 + 2)
#define TROWS 6                          // halo rows (4 + 2)
#define NREC (TROWS * TW)                // 396 records per block
// K-packed B: 7 ksteps x 2 N-tiles x 64 lanes x 8 halves
#define NKS 7
#define WB2_HALVES (NKS * 2 * 64 * 8)    // 7168 halves = 14336 B
#define WS_NEEDED ((size_t)WB2_HALVES * 2 + 16)

typedef __attribute__((ext_vector_type(8))) _Float16 half8;
typedef __attribute__((ext_vector_type(4))) float f32x4;

// Reference-exact phi (Cox-de Boor) -- fallback only
__device__ inline void kan_phi6(float xx, const float* g, const float* r1, const float* r2,
                                float* o6) {
    const float sig = 1.0f / (1.0f + __expf(-xx));
    o6[0] = xx * sig;
    float b0[7];
#pragma unroll
    for (int j = 0; j < 7; ++j) b0[j] = (xx >= g[j] && xx < g[j + 1]) ? 1.0f : 0.0f;
    float b1[6];
#pragma unroll
    for (int j = 0; j < 6; ++j)
        b1[j] = (xx - g[j]) * r1[j] * b0[j] + (g[j + 2] - xx) * r1[j + 1] * b0[j + 1];
#pragma unroll
    for (int j = 0; j < NB; ++j)
        o6[1 + j] = (xx - g[j]) * r2[j] * b1[j] + (g[j + 3] - xx) * r2[j + 1] * b1[j + 1];
}

__device__ inline void load_grid(const float* __restrict__ grid, float* g, float* r1, float* r2) {
#pragma unroll
    for (int j = 0; j < NG; ++j) g[j] = grid[j];
#pragma unroll
    for (int j = 0; j < NG - 1; ++j) r1[j] = 1.0f / (g[j + 1] - g[j]);
#pragma unroll
    for (int j = 0; j < NG - 2; ++j) r2[j] = 1.0f / (g[j + 2] - g[j]);
}

// ---------------------------------------------------------------------------
// Prep: weights -> K-packed B-fragment layout (fp16).
//   wb2[((kstep*2+nt)*64+lane)*8+e] : k_global = kstep*32 + (lane>>4)*8 + e
//   k_global -> tap = k/24, within = k%24; real iff k<216 && within<18:
//   c = within/6, j = within%6, f = c*9+tap, o = nt*16 + (lane&15)
// Thread 0 also writes {g0, invh} after wb2 (grid is uniform).
// ---------------------------------------------------------------------------
__global__ void kan_prepW(const float* __restrict__ bw, const float* __restrict__ sw,
                          const float* __restrict__ ss, const float* __restrict__ grid,
                          _Float16* __restrict__ wb) {
    int t = blockIdx.x * 256 + threadIdx.x;
    if (t >= NKS * 2 * 64) return;

    if (t == 0) {
        float* gt = (float*)(wb + WB2_HALVES);
        gt[0] = grid[0];
        gt[1] = 7.0f / (grid[7] - grid[0]);   // 1/h
    }

    const int lane = t & 63;
    const int nt = (t >> 6) & 1;
    const int kstep = t >> 7;
    const int o = nt * 16 + (lane & 15);
    const int kbase = kstep * 32 + (lane >> 4) * 8;
    half8 v8 = {0, 0, 0, 0, 0, 0, 0, 0};
#pragma unroll
    for (int e = 0; e < 8; ++e) {
        int k = kbase + e;
        float v = 0.0f;
        if (k < 216) {
            int tap = k / 24, within = k % 24;
            if (within < 18) {
                int c = within / 6, j = within % 6;
                int f = c * 9 + tap;
                int of = o * IN_FEAT + f;
                v = (j == 0) ? bw[of] : sw[of * NB + (j - 1)] * ss[of];
            }
        }
        v8[e] = (_Float16)v;
    }
    *(half8*)(wb + (size_t)t * 8) = v8;
}

// ---------------------------------------------------------------------------
// Fused kernel (R6 geometry, K-packed): block = 256 thr = 4 waves; 64 x 4 tile.
//  Phase 1: 396 halo records -> LDS, closed-form uniform B-spline.
//  Phase 2: wave wid owns row h0+wid: 4 M-tiles x 7 ksteps x 2 N -> 56 MFMA;
//           14 B-frags in regs (loaded after barrier); plain dwordx4 stores.
// ---------------------------------------------------------------------------
__global__ __launch_bounds__(256, 4) void kan_fused(const float* __restrict__ x,
                                                    const _Float16* __restrict__ wb,
                                                    float* __restrict__ out) {
    __shared__ _Float16 lPhi[NREC * RECP];   // 22176 B

    const int tid = threadIdx.x;
    const int bid = blockIdx.x;
    const int strip = bid & 3;
    const int rowg = (bid >> 2) & 63;
    const int b = bid >> 8;
    const int h0 = rowg * 4;
    const int w0 = strip * 64;

    const int lane = tid & 63;
    const int wid = tid >> 6;
    const int r = lane & 15;      // A row (pixel) / B col (channel) within tile
    const int gq = lane >> 4;     // k-quarter (0..3)

    const float* gt = (const float*)(wb + WB2_HALVES);
    const float g0 = gt[0];
    const float invh = gt[1];

    // ---- Phase 1: phi halo tile (closed-form uniform quadratic B-spline) ----
    for (int ri = tid; ri < NREC; ri += 256) {
        const int dyR = ri / TW;             // 0..5
        const int wxR = ri - dyR * TW - 1;   // -1..64
        const int hy = h0 + dyR - 1;
        const int wx = w0 + wxR;
        const bool vld = ((unsigned)hy < HH) & ((unsigned)wx < WW);

        _Float16 rec[RECE];
#pragma unroll
        for (int c = 0; c < IN_CH; ++c) {
            const float xx = vld ? x[((b * IN_CH + c) << 16) + (hy << 8) + wx] : 0.0f;
            const float sig = 1.0f / (1.0f + __expf(-xx));
            rec[c * 6] = (_Float16)(xx * sig);
            const float u = (xx - g0) * invh;
            const float fi = floorf(u);
            const int i0 = (int)fi;
            const float t = u - fi;
            const float om = 1.0f - t;
            float wA = 0.5f * om * om;          // slot i0-2
            float wC = 0.5f * t * t;            // slot i0
            float wB = 1.0f - wA - wC;          // slot i0-1
            const bool valid = (fi >= 0.0f) & (i0 <= 6);
            wA = valid ? wA : 0.0f;
            wB = valid ? wB : 0.0f;
            wC = valid ? wC : 0.0f;
#pragma unroll
            for (int j = 0; j < NB; ++j) {
                float v = (j == i0 - 2) ? wA : ((j == i0 - 1) ? wB : ((j == i0) ? wC : 0.0f));
                rec[c * 6 + 1 + j] = (_Float16)v;
            }
        }
#pragma unroll
        for (int j = 18; j < RECE; ++j) rec[j] = (_Float16)0.0f;

        half8* dst = (half8*)(lPhi + ri * RECP);
        dst[0] = *(half8*)(rec + 0);
        dst[1] = *(half8*)(rec + 8);
        dst[2] = *(half8*)(rec + 16);
    }
    __syncthreads();

    // ---- B-fragments: from global (L2-resident) AFTER the barrier ----
    half8 bf[NKS * 2];
#pragma unroll
    for (int i = 0; i < NKS * 2; ++i)
        bf[i] = *(const half8*)(wb + ((size_t)(i * 64 + lane)) * 8);

    // per-kstep chunk decode: q = kstep*4 + gq -> tap = q/3, part = q%3
    int rowoff[NKS], partoff[NKS];
    bool kvalid[NKS];
#pragma unroll
    for (int k = 0; k < NKS; ++k) {
        const int q = k * 4 + gq;
        const int tap = q / 3;               // 0..8 (q<=26), 9 if q==27
        const int part = q - tap * 3;
        kvalid[k] = (q < 27);
        const int dyk = tap / 3;             // clamp irrelevant when invalid
        const int dxk = tap - dyk * 3;
        rowoff[k] = (wid + (kvalid[k] ? dyk : 0)) * TW + (kvalid[k] ? dxk : 0);
        partoff[k] = part * 8;
    }

    // ---- Phase 2: 4 M-tiles along the wave's row ----
    const int hrow = h0 + wid;
    float* pb0 = out + ((size_t)(b * OUT_CH + r) << 16)      + (hrow << 8) + w0 + gq * 4;
    float* pb1 = out + ((size_t)(b * OUT_CH + 16 + r) << 16) + (hrow << 8) + w0 + gq * 4;
#pragma unroll
    for (int m = 0; m < 4; ++m) {
        half8 a[NKS];
#pragma unroll
        for (int k = 0; k < NKS; ++k) {
            half8 v = {0, 0, 0, 0, 0, 0, 0, 0};
            if (kvalid[k]) {
                const int ridx = rowoff[k] + m * 16 + r;
                v = *(const half8*)(lPhi + ridx * RECP + partoff[k]);
            }
            a[k] = v;
        }

        f32x4 acc0 = {0.f, 0.f, 0.f, 0.f};
        f32x4 acc1 = {0.f, 0.f, 0.f, 0.f};
#pragma unroll
        for (int k = 0; k < NKS; ++k) {
            acc0 = __builtin_amdgcn_mfma_f32_16x16x32_f16(a[k], bf[k * 2 + 0], acc0, 0, 0, 0);
            acc1 = __builtin_amdgcn_mfma_f32_16x16x32_f16(a[k], bf[k * 2 + 1], acc1, 0, 0, 0);
        }

        *(f32x4*)(pb0 + m * 16) = acc0;
        *(f32x4*)(pb1 + m * 16) = acc1;
    }
}

// ===========================================================================
// Fallback (round-1 fp32 path) if ws_size is too small for wb
// ===========================================================================
__global__ void kan_combine_weights(const float* __restrict__ bw,
                                    const float* __restrict__ sw,
                                    const float* __restrict__ ss,
                                    float* __restrict__ wc) {
    int idx = blockIdx.x * blockDim.x + threadIdx.x;
    if (idx >= IN_FEAT * 6 * OUT_CH) return;
    int o = idx & 31;
    int j = (idx >> 5) % 6;
    int f = idx / (6 * 32);
    float v;
    if (j == 0) v = bw[o * IN_FEAT + f];
    else        v = sw[(o * IN_FEAT + f) * NB + (j - 1)] * ss[o * IN_FEAT + f];
    wc[idx] = v;
}

__global__ __launch_bounds__(256) void kan_main(const float* __restrict__ x,
                                                const float* __restrict__ grid,
                                                const float* __restrict__ wc,
                                                float* __restrict__ out) {
    const int p = blockIdx.x * blockDim.x + threadIdx.x;
    const int w = p & (WW - 1);
    const int h = (p >> 8) & (HH - 1);
    const int b = p >> 16;
    float g[NG], r1[NG - 1], r2[NG - 2];
    load_grid(grid, g, r1, r2);
    float acc[OUT_CH];
#pragma unroll
    for (int o = 0; o < OUT_CH; ++o) acc[o] = 0.0f;
    const float* xb = x + b * (IN_CH * HH * WW);
    for (int c = 0; c < IN_CH; ++c) {
        const float* xc = xb + c * (HH * WW);
#pragma unroll
        for (int dy = 0; dy < 3; ++dy) {
            const int hy = h + dy - 1;
            const bool vy = (hy >= 0) && (hy < HH);
#pragma unroll
            for (int dx = 0; dx < 3; ++dx) {
                const int wx = w + dx - 1;
                const bool vld = vy && (wx >= 0) && (wx < WW);
                const float xx = vld ? xc[hy * WW + wx] : 0.0f;
                float o6[6];
                kan_phi6(xx, g, r1, r2, o6);
                const float* wf = wc + (c * 9 + dy * 3 + dx) * (6 * OUT_CH);
#pragma unroll
                for (int jj = 0; jj < 6; ++jj) {
                    const float* wj = wf + jj * OUT_CH;
#pragma unroll
                    for (int o = 0; o < OUT_CH; ++o) acc[o] += o6[jj] * wj[o];
                }
            }
        }
    }
    float* ob = out + (size_t)b * (OUT_CH * HH * WW) + h * WW + w;
#pragma unroll
    for (int o = 0; o < OUT_CH; ++o) ob[o * (HH * WW)] = acc[o];
}

// ===========================================================================
extern "C" void kernel_launch(void* const* d_in, const int* in_sizes, int n_in,
                              void* d_out, int out_size, void* d_ws, size_t ws_size,
                              hipStream_t stream) {
    const float* x    = (const float*)d_in[0];
    const float* bw   = (const float*)d_in[1];
    const float* sw   = (const float*)d_in[2];
    const float* ss   = (const float*)d_in[3];
    const float* grid = (const float*)d_in[4];
    float* out = (float*)d_out;

    if (ws_size >= WS_NEEDED) {
        _Float16* wb = (_Float16*)d_ws;
        kan_prepW<<<4, 256, 0, stream>>>(bw, sw, ss, grid, wb);
        kan_fused<<<NPIX / 256, 256, 0, stream>>>(x, wb, out);   // 2048 blocks
    } else {
        float* wc = (float*)d_ws;
        kan_combine_weights<<<(IN_FEAT * 6 * OUT_CH + 255) / 256, 256, 0, stream>>>(bw, sw, ss, wc);
        kan_main<<<NPIX / 256, 256, 0, stream>>>(x, grid, wc, out);
    }
}

// Round 11
// 43.477 us; speedup vs baseline: 1.7033x; 1.0824x over previous
//
#include <hip/hip_runtime.h>

#define IN_CH 3
#define OUT_CH 32
#define IN_FEAT 27
#define NB 5
#define NG 8
#define HH 256
#define WW 256
#define NPIX (16 * HH * WW)

// Phi record: 24 fp16 (18 real + 6 zero), stored unpadded in LDS (48 B)
#define RECE 24
#define RECP 24
#define TW 66                            // halo tile width (64 + 2)
#define TROWS 6                          // halo rows (4 + 2)
#define NREC (TROWS * TW)                // 396 records per block
// K-packed B: 7 ksteps x 2 N-tiles x 64 lanes x 8 halves
#define NKS 7
#define WB2_HALVES (NKS * 2 * 64 * 8)    // 7168 halves = 14336 B
#define WS_NEEDED ((size_t)WB2_HALVES * 2 + 16)
// store-transpose scratch: per wave 32 ch x 36 dwords (32 px + 4 pad)
#define SCR_STRIDE 36
#define SCR_WAVE (32 * SCR_STRIDE)       // 1152 dwords = 4608 B

typedef __attribute__((ext_vector_type(8))) _Float16 half8;
typedef __attribute__((ext_vector_type(4))) float f32x4;

// Reference-exact phi (Cox-de Boor) -- fallback only
__device__ inline void kan_phi6(float xx, const float* g, const float* r1, const float* r2,
                                float* o6) {
    const float sig = 1.0f / (1.0f + __expf(-xx));
    o6[0] = xx * sig;
    float b0[7];
#pragma unroll
    for (int j = 0; j < 7; ++j) b0[j] = (xx >= g[j] && xx < g[j + 1]) ? 1.0f : 0.0f;
    float b1[6];
#pragma unroll
    for (int j = 0; j < 6; ++j)
        b1[j] = (xx - g[j]) * r1[j] * b0[j] + (g[j + 2] - xx) * r1[j + 1] * b0[j + 1];
#pragma unroll
    for (int j = 0; j < NB; ++j)
        o6[1 + j] = (xx - g[j]) * r2[j] * b1[j] + (g[j + 3] - xx) * r2[j + 1] * b1[j + 1];
}

__device__ inline void load_grid(const float* __restrict__ grid, float* g, float* r1, float* r2) {
#pragma unroll
    for (int j = 0; j < NG; ++j) g[j] = grid[j];
#pragma unroll
    for (int j = 0; j < NG - 1; ++j) r1[j] = 1.0f / (g[j + 1] - g[j]);
#pragma unroll
    for (int j = 0; j < NG - 2; ++j) r2[j] = 1.0f / (g[j + 2] - g[j]);
}

// ---------------------------------------------------------------------------
// Prep: weights -> K-packed B-fragment layout (fp16), as in R10.
// ---------------------------------------------------------------------------
__global__ void kan_prepW(const float* __restrict__ bw, const float* __restrict__ sw,
                          const float* __restrict__ ss, const float* __restrict__ grid,
                          _Float16* __restrict__ wb) {
    int t = blockIdx.x * 256 + threadIdx.x;
    if (t >= NKS * 2 * 64) return;

    if (t == 0) {
        float* gt = (float*)(wb + WB2_HALVES);
        gt[0] = grid[0];
        gt[1] = 7.0f / (grid[7] - grid[0]);   // 1/h
    }

    const int lane = t & 63;
    const int nt = (t >> 6) & 1;
    const int kstep = t >> 7;
    const int o = nt * 16 + (lane & 15);
    const int kbase = kstep * 32 + (lane >> 4) * 8;
    half8 v8 = {0, 0, 0, 0, 0, 0, 0, 0};
#pragma unroll
    for (int e = 0; e < 8; ++e) {
        int k = kbase + e;
        float v = 0.0f;
        if (k < 216) {
            int tap = k / 24, within = k % 24;
            if (within < 18) {
                int c = within / 6, j = within % 6;
                int f = c * 9 + tap;
                int of = o * IN_FEAT + f;
                v = (j == 0) ? bw[of] : sw[of * NB + (j - 1)] * ss[of];
            }
        }
        v8[e] = (_Float16)v;
    }
    *(half8*)(wb + (size_t)t * 8) = v8;
}

// ---------------------------------------------------------------------------
// Fused kernel: R10 geometry + store linearization.
//  Phase 1: 396 halo records -> LDS, closed-form uniform B-spline.
//  Phase 2: per wave, 2 halves of {2 M-tiles x 14 MFMA}, then wave-private
//           LDS transpose -> 4 x 1KB stores (8 full 128B lines each).
// ---------------------------------------------------------------------------
__global__ __launch_bounds__(256, 4) void kan_fused(const float* __restrict__ x,
                                                    const _Float16* __restrict__ wb,
                                                    float* __restrict__ out) {
    __shared__ _Float16 lPhi[NREC * RECP];       // 19008 B
    __shared__ float lScr[4 * SCR_WAVE];         // 18432 B

    const int tid = threadIdx.x;
    const int bid = blockIdx.x;
    const int strip = bid & 3;
    const int rowg = (bid >> 2) & 63;
    const int b = bid >> 8;
    const int h0 = rowg * 4;
    const int w0 = strip * 64;

    const int lane = tid & 63;
    const int wid = tid >> 6;
    const int r = lane & 15;      // A row (pixel) / B col (channel) within tile
    const int gq = lane >> 4;     // k-quarter (0..3)

    const float* gt = (const float*)(wb + WB2_HALVES);
    const float g0 = gt[0];
    const float invh = gt[1];

    // ---- Phase 1: phi halo tile (closed-form uniform quadratic B-spline) ----
    for (int ri = tid; ri < NREC; ri += 256) {
        const int dyR = ri / TW;             // 0..5
        const int wxR = ri - dyR * TW - 1;   // -1..64
        const int hy = h0 + dyR - 1;
        const int wx = w0 + wxR;
        const bool vld = ((unsigned)hy < HH) & ((unsigned)wx < WW);

        _Float16 rec[RECE];
#pragma unroll
        for (int c = 0; c < IN_CH; ++c) {
            const float xx = vld ? x[((b * IN_CH + c) << 16) + (hy << 8) + wx] : 0.0f;
            const float sig = 1.0f / (1.0f + __expf(-xx));
            rec[c * 6] = (_Float16)(xx * sig);
            const float u = (xx - g0) * invh;
            const float fi = floorf(u);
            const int i0 = (int)fi;
            const float t = u - fi;
            const float om = 1.0f - t;
            float wA = 0.5f * om * om;          // slot i0-2
            float wC = 0.5f * t * t;            // slot i0
            float wB = 1.0f - wA - wC;          // slot i0-1
            const bool valid = (fi >= 0.0f) & (i0 <= 6);
            wA = valid ? wA : 0.0f;
            wB = valid ? wB : 0.0f;
            wC = valid ? wC : 0.0f;
#pragma unroll
            for (int j = 0; j < NB; ++j) {
                float v = (j == i0 - 2) ? wA : ((j == i0 - 1) ? wB : ((j == i0) ? wC : 0.0f));
                rec[c * 6 + 1 + j] = (_Float16)v;
            }
        }
#pragma unroll
        for (int j = 18; j < RECE; ++j) rec[j] = (_Float16)0.0f;

        half8* dst = (half8*)(lPhi + ri * RECP);
        dst[0] = *(half8*)(rec + 0);
        dst[1] = *(half8*)(rec + 8);
        dst[2] = *(half8*)(rec + 16);
    }
    __syncthreads();

    // ---- B-fragments: from global (L2-resident) AFTER the barrier ----
    half8 bf[NKS * 2];
#pragma unroll
    for (int i = 0; i < NKS * 2; ++i)
        bf[i] = *(const half8*)(wb + ((size_t)(i * 64 + lane)) * 8);

    // per-kstep chunk decode: q = kstep*4 + gq -> tap = q/3, part = q%3
    int rowoff[NKS], partoff[NKS];
    bool kvalid[NKS];
#pragma unroll
    for (int k = 0; k < NKS; ++k) {
        const int q = k * 4 + gq;
        const int tap = q / 3;
        const int part = q - tap * 3;
        kvalid[k] = (q < 27);
        const int dyk = tap / 3;
        const int dxk = tap - dyk * 3;
        rowoff[k] = (wid + (kvalid[k] ? dyk : 0)) * TW + (kvalid[k] ? dxk : 0);
        partoff[k] = part * 8;
    }

    // ---- Phase 2: 2 halves x {2 M-tiles, MFMA}, transpose, linear stores ----
    const int hrow = h0 + wid;
    float* lT = lScr + wid * SCR_WAVE;
    const int chl = lane >> 3;            // 0..7: channel sub-index for readback
    const int pxl = (lane & 7) * 4;       // 0..28: pixel offset for readback

#pragma unroll
    for (int h = 0; h < 2; ++h) {
        f32x4 accA0 = {0.f, 0.f, 0.f, 0.f}, accA1 = {0.f, 0.f, 0.f, 0.f};
        f32x4 accB0 = {0.f, 0.f, 0.f, 0.f}, accB1 = {0.f, 0.f, 0.f, 0.f};
#pragma unroll
        for (int mm = 0; mm < 2; ++mm) {
            const int m = h * 2 + mm;
            half8 a[NKS];
#pragma unroll
            for (int k = 0; k < NKS; ++k) {
                half8 v = {0, 0, 0, 0, 0, 0, 0, 0};
                if (kvalid[k]) {
                    const int ridx = rowoff[k] + m * 16 + r;
                    v = *(const half8*)(lPhi + ridx * RECP + partoff[k]);
                }
                a[k] = v;
            }
            if (mm == 0) {
#pragma unroll
                for (int k = 0; k < NKS; ++k) {
                    accA0 = __builtin_amdgcn_mfma_f32_16x16x32_f16(a[k], bf[k * 2 + 0], accA0, 0, 0, 0);
                    accA1 = __builtin_amdgcn_mfma_f32_16x16x32_f16(a[k], bf[k * 2 + 1], accA1, 0, 0, 0);
                }
            } else {
#pragma unroll
                for (int k = 0; k < NKS; ++k) {
                    accB0 = __builtin_amdgcn_mfma_f32_16x16x32_f16(a[k], bf[k * 2 + 0], accB0, 0, 0, 0);
                    accB1 = __builtin_amdgcn_mfma_f32_16x16x32_f16(a[k], bf[k * 2 + 1], accB1, 0, 0, 0);
                }
            }
        }

        // wave-private transpose: ch-major scratch [32][36]
        // lane (r,gq): acc{A,B}{0,1}[i] = pixel (mm*16 + gq*4 + i), channel r / 16+r
        *(f32x4*)(lT + r        * SCR_STRIDE + 0  + gq * 4) = accA0;
        *(f32x4*)(lT + (16 + r) * SCR_STRIDE + 0  + gq * 4) = accA1;
        *(f32x4*)(lT + r        * SCR_STRIDE + 16 + gq * 4) = accB0;
        *(f32x4*)(lT + (16 + r) * SCR_STRIDE + 16 + gq * 4) = accB1;

        // readback + linear stores: instr j covers 8 channels x 128B lines
#pragma unroll
        for (int j = 0; j < 4; ++j) {
            const int ch = j * 8 + chl;
            f32x4 v = *(const f32x4*)(lT + ch * SCR_STRIDE + pxl);
            float* op = out + (((size_t)(b * OUT_CH + ch)) << 16) + (hrow << 8) + w0 + h * 32 + pxl;
            *(f32x4*)op = v;
        }
    }
}

// ===========================================================================
// Fallback (round-1 fp32 path) if ws_size is too small for wb
// ===========================================================================
__global__ void kan_combine_weights(const float* __restrict__ bw,
                                    const float* __restrict__ sw,
                                    const float* __restrict__ ss,
                                    float* __restrict__ wc) {
    int idx = blockIdx.x * blockDim.x + threadIdx.x;
    if (idx >= IN_FEAT * 6 * OUT_CH) return;
    int o = idx & 31;
    int j = (idx >> 5) % 6;
    int f = idx / (6 * 32);
    float v;
    if (j == 0) v = bw[o * IN_FEAT + f];
    else        v = sw[(o * IN_FEAT + f) * NB + (j - 1)] * ss[o * IN_FEAT + f];
    wc[idx] = v;
}

__global__ __launch_bounds__(256) void kan_main(const float* __restrict__ x,
                                                const float* __restrict__ grid,
                                                const float* __restrict__ wc,
                                                float* __restrict__ out) {
    const int p = blockIdx.x * blockDim.x + threadIdx.x;
    const int w = p & (WW - 1);
    const int h = (p >> 8) & (HH - 1);
    const int b = p >> 16;
    float g[NG], r1[NG - 1], r2[NG - 2];
    load_grid(grid, g, r1, r2);
    float acc[OUT_CH];
#pragma unroll
    for (int o = 0; o < OUT_CH; ++o) acc[o] = 0.0f;
    const float* xb = x + b * (IN_CH * HH * WW);
    for (int c = 0; c < IN_CH; ++c) {
        const float* xc = xb + c * (HH * WW);
#pragma unroll
        for (int dy = 0; dy < 3; ++dy) {
            const int hy = h + dy - 1;
            const bool vy = (hy >= 0) && (hy < HH);
#pragma unroll
            for (int dx = 0; dx < 3; ++dx) {
                const int wx = w + dx - 1;
                const bool vld = vy && (wx >= 0) && (wx < WW);
                const float xx = vld ? xc[hy * WW + wx] : 0.0f;
                float o6[6];
                kan_phi6(xx, g, r1, r2, o6);
                const float* wf = wc + (c * 9 + dy * 3 + dx) * (6 * OUT_CH);
#pragma unroll
                for (int jj = 0; jj < 6; ++jj) {
                    const float* wj = wf + jj * OUT_CH;
#pragma unroll
                    for (int o = 0; o < OUT_CH; ++o) acc[o] += o6[jj] * wj[o];
                }
            }
        }
    }
    float* ob = out + (size_t)b * (OUT_CH * HH * WW) + h * WW + w;
#pragma unroll
    for (int o = 0; o < OUT_CH; ++o) ob[o * (HH * WW)] = acc[o];
}

// ===========================================================================
extern "C" void kernel_launch(void* const* d_in, const int* in_sizes, int n_in,
                              void* d_out, int out_size, void* d_ws, size_t ws_size,
                              hipStream_t stream) {
    const float* x    = (const float*)d_in[0];
    const float* bw   = (const float*)d_in[1];
    const float* sw   = (const float*)d_in[2];
    const float* ss   = (const float*)d_in[3];
    const float* grid = (const float*)d_in[4];
    float* out = (float*)d_out;

    if (ws_size >= WS_NEEDED) {
        _Float16* wb = (_Float16*)d_ws;
        kan_prepW<<<4, 256, 0, stream>>>(bw, sw, ss, grid, wb);
        kan_fused<<<NPIX / 256, 256, 0, stream>>>(x, wb, out);   // 2048 blocks
    } else {
        float* wc = (float*)d_ws;
        kan_combine_weights<<<(IN_FEAT * 6 * OUT_CH + 255) / 256, 256, 0, stream>>>(bw, sw, ss, wc);
        kan_main<<<NPIX / 256, 256, 0, stream>>>(x, grid, wc, out);
    }
}